// Round 6
// baseline (5205.878 us; speedup 1.0000x reference)
//
#include <hip/hip_runtime.h>

#define T_STEPS 8192
#define BATCH   128
#define HID     128
#define SPLIT   4
#define CHUNK   (HID / SPLIT)     // 32 floats of W2 column per thread
#define NTHR    (HID * SPLIT)     // 512 threads = 8 waves

// tanh(z) = sign(z) * (1 - e^{-2|z|}) / (1 + e^{-2|z|})  -- no overflow path
__device__ __forceinline__ float fast_tanh(float z) {
    float az = fabsf(z);
    float e  = __expf(-2.0f * az);
    float r  = __fdividef(1.0f - e, 1.0f + e);
    return copysignf(r, z);
}

// wave64 sum via DPP (VALU-only, ~6 dependent adds), result broadcast from lane 63.
__device__ __forceinline__ float wave64_sum(float x) {
#define DPP_ADD(ctrl) do {                                                        \
        int t_ = __builtin_amdgcn_update_dpp(0, __builtin_bit_cast(int, x),       \
                                             (ctrl), 0xf, 0xf, false);            \
        x += __builtin_bit_cast(float, t_); } while (0)
    DPP_ADD(0x111);  // row_shr:1
    DPP_ADD(0x112);  // row_shr:2
    DPP_ADD(0x114);  // row_shr:4
    DPP_ADD(0x118);  // row_shr:8  -> lane 15/31/47/63 hold row sums
    DPP_ADD(0x142);  // row_bcast:15 -> lanes 31, 63 hold half sums
    DPP_ADD(0x143);  // row_bcast:31 -> lane 63 holds full sum
#undef DPP_ADD
    int s_ = __builtin_amdgcn_readlane(__builtin_bit_cast(int, x), 63);
    return __builtin_bit_cast(float, s_);
}

__device__ __forceinline__ float bcast_lane(float v, int l) {
    int r = __builtin_amdgcn_readlane(__builtin_bit_cast(int, v), l);
    return __builtin_bit_cast(float, r);
}

__global__ __launch_bounds__(NTHR, 2) void odenet_scan(
    const float* __restrict__ x,
    const float* __restrict__ W1, const float* __restrict__ b1,
    const float* __restrict__ W2, const float* __restrict__ b2,
    const float* __restrict__ W3, const float* __restrict__ b3,
    float* __restrict__ out) {

    const int b    = blockIdx.x;       // batch element
    const int tid  = threadIdx.x;
    const int s    = tid >> 7;         // k-split index 0..3 (uniform per wave-pair)
    const int j    = tid & (HID - 1);  // hidden unit 0..127
    const int lane = tid & 63;

    __shared__ __align__(16) float h1buf[HID];
    __shared__ __align__(16) float pbuf[NTHR];   // layout [s*HID + j] (conflict-free)

    // ---- W2 fragment: rows [CHUNK*s, CHUNK*(s+1)) of column j, 32 scalars ----
    const float* col = W2 + j;         // column j, row stride HID
    const int kb = CHUNK * s;
#define LW(k) col[(kb + (k)) * HID]
    float w00 = LW( 0), w01 = LW( 1), w02 = LW( 2), w03 = LW( 3);
    float w04 = LW( 4), w05 = LW( 5), w06 = LW( 6), w07 = LW( 7);
    float w08 = LW( 8), w09 = LW( 9), w10_ = LW(10), w11_ = LW(11);
    float w12 = LW(12), w13 = LW(13), w14 = LW(14), w15 = LW(15);
    float w16 = LW(16), w17 = LW(17), w18 = LW(18), w19 = LW(19);
    float w20 = LW(20), w21 = LW(21), w22 = LW(22), w23 = LW(23);
    float w24 = LW(24), w25 = LW(25), w26 = LW(26), w27 = LW(27);
    float w28 = LW(28), w29 = LW(29), w30 = LW(30), w31 = LW(31);
#undef LW
    float w10 = W1[j], w11 = W1[HID + j], b1j = b1[j];
    float b2a = b2[lane], b2b = b2[lane + 64];
    float w3a = W3[lane], w3b = W3[lane + 64];
    float b3v = b3[0];

#define PIN8(a,b_,c,d,e,f,g,h) asm volatile("" : "+v"(a),"+v"(b_),"+v"(c),      \
        "+v"(d),"+v"(e),"+v"(f),"+v"(g),"+v"(h))
    PIN8(w00, w01, w02, w03, w04, w05, w06, w07);
    PIN8(w08, w09, w10_, w11_, w12, w13, w14, w15);
    PIN8(w16, w17, w18, w19, w20, w21, w22, w23);
    PIN8(w24, w25, w26, w27, w28, w29, w30, w31);
    PIN8(w10, w11, b1j, b2a, b2b, w3a, w3b, b3v);
#undef PIN8

    float y    = 0.0f;
    float xbuf = 0.0f;   // waves 0-1: lane l holds x[(tblk+l)*B + b]
    float ybuf = 0.0f;   // wave 0: lane l holds y_{tblk+l+1}
    if (tid == 0) out[b] = 0.0f;       // y_0 = 0

    for (int t = 0; t < T_STEPS - 1; ++t) {
        const int tm = t & 63;
        // ---- phase A (waves 0-1): h1[j] = tanh(x*W1[0,j] + y*W1[1,j] + b1[j])
        if (s == 0) {
            if (tm == 0)                       // one 64-step x block per 64 steps
                xbuf = x[(t + lane) * BATCH + b];
            float xv = bcast_lane(xbuf, tm);   // uniform lane index (SGPR)
            h1buf[j] = fast_tanh(fmaf(xv, w10, fmaf(y, w11, b1j)));
        }
        __syncthreads();   // h1 ready; also orders prev C-reads before B-writes

        // ---- phase B: h1 chunk via ONE ds_read_b32 + SGPR broadcast.
        // R5 post-mortem: 8 waves x 8 ds_read_b128 broadcasts = 64 LDS instrs
        // x ~12 cyc ~= 770 cyc/step of shared per-CU LDS pipe -- the real
        // bottleneck. Here: lane l reads h1[32s + (l&31)] (2-way aliased,
        // conflict-free), 32 v_readlane -> SGPRs, FMAs take SGPR operand.
        // LDS pipe cost for h1 delivery: 64 instrs -> 8 instrs.
        float h1v = h1buf[(s << 5) | (lane & 31)];
        float a0 = 0.f, a1 = 0.f, a2 = 0.f, a3 = 0.f;
#define H1(k) __builtin_bit_cast(float, __builtin_amdgcn_readlane(              \
                                     __builtin_bit_cast(int, h1v), (k)))
        a0 = fmaf(H1( 0), w00, a0);  a1 = fmaf(H1( 1), w01, a1);
        a2 = fmaf(H1( 2), w02, a2);  a3 = fmaf(H1( 3), w03, a3);
        a0 = fmaf(H1( 4), w04, a0);  a1 = fmaf(H1( 5), w05, a1);
        a2 = fmaf(H1( 6), w06, a2);  a3 = fmaf(H1( 7), w07, a3);
        a0 = fmaf(H1( 8), w08, a0);  a1 = fmaf(H1( 9), w09, a1);
        a2 = fmaf(H1(10), w10_, a2); a3 = fmaf(H1(11), w11_, a3);
        a0 = fmaf(H1(12), w12, a0);  a1 = fmaf(H1(13), w13, a1);
        a2 = fmaf(H1(14), w14, a2);  a3 = fmaf(H1(15), w15, a3);
        a0 = fmaf(H1(16), w16, a0);  a1 = fmaf(H1(17), w17, a1);
        a2 = fmaf(H1(18), w18, a2);  a3 = fmaf(H1(19), w19, a3);
        a0 = fmaf(H1(20), w20, a0);  a1 = fmaf(H1(21), w21, a1);
        a2 = fmaf(H1(22), w22, a2);  a3 = fmaf(H1(23), w23, a3);
        a0 = fmaf(H1(24), w24, a0);  a1 = fmaf(H1(25), w25, a1);
        a2 = fmaf(H1(26), w26, a2);  a3 = fmaf(H1(27), w27, a3);
        a0 = fmaf(H1(28), w28, a0);  a1 = fmaf(H1(29), w29, a1);
        a2 = fmaf(H1(30), w30, a2);  a3 = fmaf(H1(31), w31, a3);
#undef H1
        pbuf[s * HID + j] = (a0 + a1) + (a2 + a3);
        __syncthreads();   // partials ready

        // ---- phase C (waves 0-1; both compute identical dy -> y replicated)
        if (s == 0) {
            float sa = pbuf[0 * HID + lane]      + pbuf[1 * HID + lane]
                     + pbuf[2 * HID + lane]      + pbuf[3 * HID + lane];
            float sb = pbuf[0 * HID + lane + 64] + pbuf[1 * HID + lane + 64]
                     + pbuf[2 * HID + lane + 64] + pbuf[3 * HID + lane + 64];
            float c = fmaf(w3a, fast_tanh(sa + b2a), w3b * fast_tanh(sb + b2b));
            y += wave64_sum(c) + b3v;               // DT = 1.0

            // capture y_{t+1} in lane tm (v_cndmask, no divergence)
            ybuf = (lane == tm) ? y : ybuf;
            // flush 64 states once per 64 steps (wave 0 only): y_{t-62..t+1}
            if (tm == 63 && tid < 64)
                out[(t - 62 + lane) * BATCH + b] = ybuf;
        }
    }
    // tail: steps t=8128..8190 captured y_8129..y_8191 in lanes 0..62 (wave 0)
    if (tid < 63)
        out[(T_STEPS - 63 + lane) * BATCH + b] = ybuf;
}

extern "C" void kernel_launch(void* const* d_in, const int* in_sizes, int n_in,
                              void* d_out, int out_size, void* d_ws, size_t ws_size,
                              hipStream_t stream) {
    const float* x  = (const float*)d_in[0];
    const float* W1 = (const float*)d_in[1];
    const float* b1 = (const float*)d_in[2];
    const float* W2 = (const float*)d_in[3];
    const float* b2 = (const float*)d_in[4];
    const float* W3 = (const float*)d_in[5];
    const float* b3 = (const float*)d_in[6];

    odenet_scan<<<dim3(BATCH), dim3(NTHR), 0, stream>>>(
        x, W1, b1, W2, b2, W3, b3, (float*)d_out);
}